// Round 1
// baseline (872.170 us; speedup 1.0000x reference)
//
#include <hip/hip_runtime.h>
#include <math.h>

// SimpleGCN R13: edge-parallel bucketed aggregation.
//  - R12 k_agg_fuse/k_agg_pool were latency-bound (VALU 36%, HBM 9.6%,
//    0 bank conflicts): one wave per node, serial offsets->csr->gather chain.
//  - Now: one block per 64-node bucket streams its contiguous `staged` slab
//    (already (src<<6)|dl, bucket-grouped) and accumulates rows into LDS
//    fp32 acc[64][68] via ds_add_f32. No csr, no offsets, no local_sort.
//    Feature f=4c+j stored at col 16j+c (bank-spread for ds_add).
//  - dinv (degree count) merged into GEMM1 kernel (per-bucket 64-row tiles).
//  - agg1 keeps fused GEMM2 (W2 cols in VGPRs, bcast b128 h reads);
//    agg2 folds mean into 8-way gpart atomics (pbuf/mean_final gone).
//  - 7 dispatches (was 9).

#define CH 4096
#define MAXNB 1024

__device__ __forceinline__ float bf2f(unsigned short u) {
    return __uint_as_float(((unsigned)u) << 16);
}
__device__ __forceinline__ unsigned short f2bf(float x) {
    unsigned b = __float_as_uint(x);
    return (unsigned short)((b + 0x7FFF + ((b >> 16) & 1)) >> 16);  // RNE
}

__global__ __launch_bounds__(256) void k_bucket_hist(const int* __restrict__ dst,
                                                     int* __restrict__ histmat,
                                                     int E, int NB) {
    __shared__ int ih[MAXNB];
    int t = threadIdx.x;
    for (int k = t; k < NB; k += 256) ih[k] = 0;
    __syncthreads();
    int base = blockIdx.x * CH;
    for (int i = 0; i < CH; i += 256) {
        int e = base + i + t;
        if (e < E) atomicAdd(&ih[dst[e] >> 6], 1);
    }
    __syncthreads();
    for (int k = t; k < NB; k += 256) histmat[(size_t)blockIdx.x * NB + k] = ih[k];
}

// ONE block, 1024 threads: per-bucket exclusive prefix over chunks (in-place,
// coalesced, unroll-8), in-LDS scan of bucket totals -> bstart; zero gpart.
__global__ __launch_bounds__(1024) void k_scan(int* __restrict__ histmat,
                                               int* __restrict__ bstart,
                                               float* __restrict__ gpart,
                                               int NB, int nch, int E) {
    __shared__ int sc[1024];
    int t = threadIdx.x;
    int run = 0;
    if (t < NB) {
        int b = 0;
        for (; b + 8 <= nch; b += 8) {
            int v[8];
#pragma unroll
            for (int u = 0; u < 8; u++) v[u] = histmat[(size_t)(b + u) * NB + t];
#pragma unroll
            for (int u = 0; u < 8; u++) {
                int x = v[u];
                histmat[(size_t)(b + u) * NB + t] = run;
                run += x;
            }
        }
        for (; b < nch; b++) {
            int x = histmat[(size_t)b * NB + t];
            histmat[(size_t)b * NB + t] = run;
            run += x;
        }
    }
    sc[t] = (t < NB) ? run : 0;
    __syncthreads();
    for (int off = 1; off < 1024; off <<= 1) {
        int x = (t >= off) ? sc[t - off] : 0;
        __syncthreads();
        sc[t] += x;
        __syncthreads();
    }
    if (t < NB) bstart[t] = sc[t] - run;  // exclusive
    if (t == 0) bstart[NB] = E;
    if (t < 512) gpart[t] = 0.f;
}

__global__ __launch_bounds__(256) void k_bucket_scatter(const int* __restrict__ src,
                                                        const int* __restrict__ dst,
                                                        const int* __restrict__ histmat,
                                                        const int* __restrict__ bstart,
                                                        int* __restrict__ staged,
                                                        int E, int NB) {
    __shared__ int cur[MAXNB];
    int t = threadIdx.x;
    for (int k = t; k < NB; k += 256)
        cur[k] = bstart[k] + histmat[(size_t)blockIdx.x * NB + k];
    __syncthreads();
    int base = blockIdx.x * CH;
    for (int i = 0; i < CH; i += 256) {
        int e = base + i + t;
        if (e < E) {
            int d = dst[e];
            int pos = atomicAdd(&cur[d >> 6], 1);
            staged[pos] = (src[e] << 6) | (d & 63);  // n<=65536 -> fits
        }
    }
}

// Per-bucket: count degrees from staged slab -> dinv; then 64-row GEMM1 tile:
// y1[r,:] = f2bf(dinv[r] * (X[r,:] @ W1)). 4 sub-tiles of 16 rows.
__global__ __launch_bounds__(256) void k_dinv_gemm(const float* __restrict__ X,
                                                   const float* __restrict__ W1,
                                                   const int* __restrict__ staged,
                                                   const int* __restrict__ bstart,
                                                   float* __restrict__ dinv,
                                                   unsigned short* __restrict__ Y, int n) {
    __shared__ float Ws[64 * 64];
    __shared__ float xs[16][64];
    __shared__ int cnt[64];
    __shared__ float dvs[64];
    int t = threadIdx.x, w = t >> 6, f = t & 63;
    int kb = blockIdx.x;
    if (t < 64) cnt[t] = 0;
    {
        const float4* W4 = (const float4*)W1;
        float4* Ws4 = (float4*)Ws;
#pragma unroll
        for (int j = 0; j < 4; j++) Ws4[t + 256 * j] = W4[t + 256 * j];
    }
    __syncthreads();
    int beg = bstart[kb], end = bstart[kb + 1];
    for (int e = beg + t; e < end; e += 256) atomicAdd(&cnt[staged[e] & 63], 1);
    __syncthreads();
    if (t < 64) {
        float dv = 1.0f / sqrtf((float)(cnt[t] + 1));  // + self-loop
        dvs[t] = dv;
        int node = kb * 64 + t;
        if (node < n) dinv[node] = dv;
    }
    __syncthreads();
    for (int sub = 0; sub < 4; sub++) {
        int rb = kb * 64 + sub * 16;
#pragma unroll
        for (int i = 0; i < 4; i++) {
            int r = rb + w * 4 + i;
            xs[w * 4 + i][f] = (r < n) ? X[(size_t)r * 64 + f] : 0.f;
        }
        __syncthreads();
        float acc0 = 0.f, acc1 = 0.f, acc2 = 0.f, acc3 = 0.f;
#pragma unroll
        for (int kq = 0; kq < 16; kq++) {
            float wv0 = Ws[(4 * kq + 0) * 64 + f];
            float wv1 = Ws[(4 * kq + 1) * 64 + f];
            float wv2 = Ws[(4 * kq + 2) * 64 + f];
            float wv3 = Ws[(4 * kq + 3) * 64 + f];
            float4 x0 = *(const float4*)&xs[w * 4 + 0][4 * kq];
            float4 x1 = *(const float4*)&xs[w * 4 + 1][4 * kq];
            float4 x2 = *(const float4*)&xs[w * 4 + 2][4 * kq];
            float4 x3 = *(const float4*)&xs[w * 4 + 3][4 * kq];
            acc0 += x0.x * wv0 + x0.y * wv1 + x0.z * wv2 + x0.w * wv3;
            acc1 += x1.x * wv0 + x1.y * wv1 + x1.z * wv2 + x1.w * wv3;
            acc2 += x2.x * wv0 + x2.y * wv1 + x2.z * wv2 + x2.w * wv3;
            acc3 += x3.x * wv0 + x3.y * wv1 + x3.z * wv2 + x3.w * wv3;
        }
        float av[4] = {acc0, acc1, acc2, acc3};
#pragma unroll
        for (int i = 0; i < 4; i++) {
            int r = rb + w * 4 + i;
            if (r < n) Y[(size_t)r * 64 + f] = f2bf(dvs[sub * 16 + w * 4 + i] * av[i]);
        }
        __syncthreads();
    }
}

// Layer-1 aggregate (edge-parallel, LDS atomics) + fused GEMM2.
// acc layout: feature f=4c+j of node dl at accL[dl*68 + 16*j + c].
__global__ __launch_bounds__(256) void k_agg1(const unsigned short* __restrict__ Yin,
                                              const float* __restrict__ dinv,
                                              const float* __restrict__ b1,
                                              const int* __restrict__ staged,
                                              const int* __restrict__ bstart,
                                              const float* __restrict__ W2,
                                              unsigned short* __restrict__ Yout, int n) {
    __shared__ float accL[64 * 68];  // 17408 B
    __shared__ float dvs[64];
    int t = threadIdx.x, w = t >> 6, l = t & 63;
    int kb = blockIdx.x;
    for (int i = t; i < 64 * 68; i += 256) accL[i] = 0.f;
    if (t < 64) {
        int node = kb * 64 + t;
        dvs[t] = (node < n) ? dinv[node] : 0.f;
    }
    __syncthreads();
    // stream slab: slot S handles edges S*4+u per 64-edge window, pipelined.
    int beg = bstart[kb], end = bstart[kb + 1];
    int c = l & 15;
    int S = t >> 4;  // 0..15
    const ushort4* Y4 = (const ushort4*)Yin;
    int eb = beg + S * 4;
    int pk[4];
#pragma unroll
    for (int u = 0; u < 4; u++) pk[u] = (eb + u < end) ? staged[eb + u] : -1;
    for (; eb < end;) {
        int en = eb + 64;
        int pn[4];
#pragma unroll
        for (int u = 0; u < 4; u++) pn[u] = (en + u < end) ? staged[en + u] : -1;
#pragma unroll
        for (int u = 0; u < 4; u++) {
            int p = pk[u];
            if (p >= 0) {
                int s = p >> 6, dl = p & 63;
                ushort4 v = Y4[(size_t)s * 16 + c];
                float* ap = &accL[dl * 68 + c];
                atomicAdd(ap + 0,  bf2f(v.x));
                atomicAdd(ap + 16, bf2f(v.y));
                atomicAdd(ap + 32, bf2f(v.z));
                atomicAdd(ap + 48, bf2f(v.w));
            }
        }
#pragma unroll
        for (int u = 0; u < 4; u++) pk[u] = pn[u];
        eb = en;
    }
    __syncthreads();
    // (a) h in place: h' = dv * relu(dv*(acc+self) + b1)   (dv twice: GCN norm
    //     + layer-2 producer scale commuted through the row-GEMM).
    {
        int m = l;
        int fm = ((m & 15) << 2) | (m >> 4);
        float bb = b1[fm];
#pragma unroll
        for (int i = 0; i < 16; i++) {
            int r = w * 16 + i;
            int node = kb * 64 + r;
            float dv = dvs[r];
            float self = (node < n) ? bf2f(Yin[(size_t)node * 64 + fm]) : 0.f;
            float hv = fmaxf(dv * (accL[r * 68 + m] + self) + bb, 0.f);
            accL[r * 68 + m] = dv * hv;
        }
    }
    __syncthreads();
    // (b) GEMM2: lane l = out feature; W2 column (swizzle-ordered) in VGPRs;
    //     h rows via broadcast float4 LDS reads.
    float wcol[64];
#pragma unroll
    for (int m2 = 0; m2 < 64; m2++) {
        int fm2 = ((m2 & 15) << 2) | (m2 >> 4);
        wcol[m2] = W2[fm2 * 64 + l];
    }
    for (int i = 0; i < 16; i++) {
        int r = w * 16 + i;
        int node = kb * 64 + r;
        float a2 = 0.f;
#pragma unroll
        for (int g = 0; g < 16; g++) {
            float4 h4 = *(const float4*)&accL[r * 68 + 4 * g];
            a2 += h4.x * wcol[4 * g + 0] + h4.y * wcol[4 * g + 1]
                + h4.z * wcol[4 * g + 2] + h4.w * wcol[4 * g + 3];
        }
        if (node < n) Yout[(size_t)node * 64 + l] = f2bf(a2);
    }
}

// Layer-2 aggregate + fused mean partials into 8-way-split gpart.
__global__ __launch_bounds__(256) void k_agg2(const unsigned short* __restrict__ Yin,
                                              const float* __restrict__ dinv,
                                              const float* __restrict__ b2,
                                              const int* __restrict__ staged,
                                              const int* __restrict__ bstart,
                                              float* __restrict__ gpart, int n) {
    __shared__ float accL[64 * 68];
    __shared__ float dvs[64];
    __shared__ float part[4][64];
    int t = threadIdx.x, w = t >> 6, l = t & 63;
    int kb = blockIdx.x;
    for (int i = t; i < 64 * 68; i += 256) accL[i] = 0.f;
    if (t < 64) {
        int node = kb * 64 + t;
        dvs[t] = (node < n) ? dinv[node] : 0.f;
    }
    __syncthreads();
    int beg = bstart[kb], end = bstart[kb + 1];
    int c = l & 15;
    int S = t >> 4;
    const ushort4* Y4 = (const ushort4*)Yin;
    int eb = beg + S * 4;
    int pk[4];
#pragma unroll
    for (int u = 0; u < 4; u++) pk[u] = (eb + u < end) ? staged[eb + u] : -1;
    for (; eb < end;) {
        int en = eb + 64;
        int pn[4];
#pragma unroll
        for (int u = 0; u < 4; u++) pn[u] = (en + u < end) ? staged[en + u] : -1;
#pragma unroll
        for (int u = 0; u < 4; u++) {
            int p = pk[u];
            if (p >= 0) {
                int s = p >> 6, dl = p & 63;
                ushort4 v = Y4[(size_t)s * 16 + c];
                float* ap = &accL[dl * 68 + c];
                atomicAdd(ap + 0,  bf2f(v.x));
                atomicAdd(ap + 16, bf2f(v.y));
                atomicAdd(ap + 32, bf2f(v.z));
                atomicAdd(ap + 48, bf2f(v.w));
            }
        }
#pragma unroll
        for (int u = 0; u < 4; u++) pk[u] = pn[u];
        eb = en;
    }
    __syncthreads();
    int m = l;
    int fm = ((m & 15) << 2) | (m >> 4);
    float bb = b2[fm];
    float local = 0.f;
#pragma unroll
    for (int i = 0; i < 16; i++) {
        int r = w * 16 + i;
        int node = kb * 64 + r;
        if (node < n) {
            float dv = dvs[r];
            float self = bf2f(Yin[(size_t)node * 64 + fm]);
            local += fmaxf(dv * (accL[r * 68 + m] + self) + bb, 0.f);
        }
    }
    part[w][m] = local;
    __syncthreads();
    if (t < 64) {
        float tot = part[0][t] + part[1][t] + part[2][t] + part[3][t];
        int fm2 = ((t & 15) << 2) | (t >> 4);
        atomicAdd(&gpart[((kb & 7) << 6) + fm2], tot);
    }
}

__global__ void k_readout(const float* __restrict__ gpart, const float* __restrict__ Wr,
                          const float* __restrict__ br, float* __restrict__ out,
                          float invn) {
    __shared__ float gl[64];
    int t = threadIdx.x;
    if (t < 64) {
        float s = 0.f;
#pragma unroll
        for (int j = 0; j < 8; j++) s += gpart[j * 64 + t];
        gl[t] = s * invn;
    }
    __syncthreads();
    float acc = br[t];
#pragma unroll
    for (int k = 0; k < 64; k++) acc += gl[k] * Wr[k * 128 + t];
    out[t] = acc;
}

extern "C" void kernel_launch(void* const* d_in, const int* in_sizes, int n_in,
                              void* d_out, int out_size, void* d_ws, size_t ws_size,
                              hipStream_t stream) {
    const float* x  = (const float*)d_in[0];
    const int*   ei = (const int*)d_in[1];   // int32 on device (JAX x64 off)
    const float* W1 = (const float*)d_in[2];
    const float* b1 = (const float*)d_in[3];
    const float* W2 = (const float*)d_in[4];
    const float* b2 = (const float*)d_in[5];
    const float* Wr = (const float*)d_in[6];
    const float* br = (const float*)d_in[7];
    float* out = (float*)d_out;

    int n = in_sizes[0] / 64;   // 50000
    int E = in_sizes[1] / 2;    // 800000
    const int* src = ei;
    const int* dst = ei + E;

    int NB  = (n + 63) / 64;       // 782 buckets of 64 nodes
    int nch = (E + CH - 1) / CH;   // 196 chunks

    // workspace layout (~17 MB)
    char* p = (char*)d_ws;
    unsigned short* y1 = (unsigned short*)p; p += (size_t)n * 64 * sizeof(unsigned short);
    unsigned short* y2 = (unsigned short*)p; p += (size_t)n * 64 * sizeof(unsigned short);
    float* dinv = (float*)p;   p += (size_t)n * sizeof(float);
    float* gpart = (float*)p;  p += 512 * sizeof(float);
    int* staged = (int*)p;     p += (size_t)E * sizeof(int);
    int* histmat = (int*)p;    p += (size_t)nch * NB * sizeof(int);
    int* bstart = (int*)p;     p += (size_t)(NB + 1) * sizeof(int);

    k_bucket_hist<<<nch, 256, 0, stream>>>(dst, histmat, E, NB);
    k_scan<<<1, 1024, 0, stream>>>(histmat, bstart, gpart, NB, nch, E);
    k_bucket_scatter<<<nch, 256, 0, stream>>>(src, dst, histmat, bstart, staged, E, NB);
    k_dinv_gemm<<<NB, 256, 0, stream>>>(x, W1, staged, bstart, dinv, y1, n);
    k_agg1<<<NB, 256, 0, stream>>>(y1, dinv, b1, staged, bstart, W2, y2, n);
    k_agg2<<<NB, 256, 0, stream>>>(y2, dinv, b2, staged, bstart, gpart, n);
    k_readout<<<1, 128, 0, stream>>>(gpart, Wr, br, out, 1.0f / (float)n);
}

// Round 2
// 357.793 us; speedup vs baseline: 2.4376x; 2.4376x over previous
//
#include <hip/hip_runtime.h>
#include <math.h>

// SimpleGCN R14: revert to R12 (measured 230.9us) + two targeted changes.
//  - R13 post-mortem: LDS fp32 atomicAdd aggregation = CAS-loop serialization
//    (361us, VALU 3.7%). Reverted to R12's wave-per-node gather (verbatim).
//  - R12 k_agg_fuse was LDS-issue-bound: epilogue read Ws per-FMA ->
//    ~2445 LDS cycles/block ~= measured 50.6us. Now W2 column lives in
//    VGPRs (wcol[64], coalesced global loads, L1-resident, hidden under
//    gather); epilogue LDS = 16 bcast b128 reads + 1 write per wave.
//  - k_agg_pool pools directly into 8-way-split gpart via global atomicAdd
//    (pattern validated in R13): pbuf + k_mean_final deleted. 8 dispatches.

#define CH 4096    // edges per chunk-block in hist/scatter
#define MAXNB 1024 // NB = ceil(n/64) <= 1024 (n <= 65536)

__device__ __forceinline__ float bf2f(unsigned short u) {
    return __uint_as_float(((unsigned)u) << 16);
}
__device__ __forceinline__ unsigned short f2bf(float x) {
    unsigned b = __float_as_uint(x);
    return (unsigned short)((b + 0x7FFF + ((b >> 16) & 1)) >> 16);  // RNE
}

__global__ __launch_bounds__(256) void k_bucket_hist(const int* __restrict__ dst,
                                                     int* __restrict__ histmat,
                                                     int E, int NB) {
    __shared__ int ih[MAXNB];
    int t = threadIdx.x;
    for (int k = t; k < NB; k += 256) ih[k] = 0;
    __syncthreads();
    int base = blockIdx.x * CH;
    for (int i = 0; i < CH; i += 256) {
        int e = base + i + t;
        if (e < E) atomicAdd(&ih[dst[e] >> 6], 1);
    }
    __syncthreads();
    for (int k = t; k < NB; k += 256) histmat[(size_t)blockIdx.x * NB + k] = ih[k];
}

// ONE block, 1024 threads (thread = bucket, NB<=1024): per-bucket exclusive
// prefix over chunks (in-place in histmat, coalesced, unroll-8), then an
// in-LDS Hillis-Steele scan of bucket totals -> bstart. Also zeroes gpart.
__global__ __launch_bounds__(1024) void k_scan(int* __restrict__ histmat,
                                               int* __restrict__ bstart,
                                               int* __restrict__ offsets,
                                               float* __restrict__ gpart,
                                               int NB, int nch, int E, int n) {
    __shared__ int sc[1024];
    int t = threadIdx.x;
    int run = 0;
    if (t < NB) {
        int b = 0;
        for (; b + 8 <= nch; b += 8) {
            int v[8];
#pragma unroll
            for (int u = 0; u < 8; u++) v[u] = histmat[(size_t)(b + u) * NB + t];
#pragma unroll
            for (int u = 0; u < 8; u++) {
                int x = v[u];
                histmat[(size_t)(b + u) * NB + t] = run;
                run += x;
            }
        }
        for (; b < nch; b++) {
            int x = histmat[(size_t)b * NB + t];
            histmat[(size_t)b * NB + t] = run;
            run += x;
        }
    }
    sc[t] = (t < NB) ? run : 0;
    __syncthreads();
    for (int off = 1; off < 1024; off <<= 1) {
        int x = (t >= off) ? sc[t - off] : 0;
        __syncthreads();
        sc[t] += x;
        __syncthreads();
    }
    if (t < NB) bstart[t] = sc[t] - run;  // exclusive
    if (t == 0) { bstart[NB] = E; offsets[n] = E; }
    if (t < 512) gpart[t] = 0.f;
}

__global__ __launch_bounds__(256) void k_bucket_scatter(const int* __restrict__ src,
                                                        const int* __restrict__ dst,
                                                        const int* __restrict__ histmat,
                                                        const int* __restrict__ bstart,
                                                        int* __restrict__ staged,
                                                        int E, int NB) {
    __shared__ int cur[MAXNB];
    int t = threadIdx.x;
    for (int k = t; k < NB; k += 256)
        cur[k] = bstart[k] + histmat[(size_t)blockIdx.x * NB + k];
    __syncthreads();
    int base = blockIdx.x * CH;
    for (int i = 0; i < CH; i += 256) {
        int e = base + i + t;
        if (e < E) {
            int d = dst[e];
            int pos = atomicAdd(&cur[d >> 6], 1);
            staged[pos] = (src[e] << 6) | (d & 63);  // n<=65536 -> fits
        }
    }
}

// one block per bucket: counting-sort staged run into node-granular ushort
// CSR; emit per-node offsets + dinv.
__global__ __launch_bounds__(256) void k_local_sort(const int* __restrict__ staged,
                                                    const int* __restrict__ bstart,
                                                    unsigned short* __restrict__ csr,
                                                    int* __restrict__ offsets,
                                                    float* __restrict__ dinv, int n) {
    __shared__ int cnt[64];
    __shared__ int pos[64];
    __shared__ int cur[64];
    int t = threadIdx.x;
    if (t < 64) cnt[t] = 0;
    __syncthreads();
    int k = blockIdx.x;
    int beg = bstart[k], end = bstart[k + 1];
    for (int e = beg + t; e < end; e += 256) atomicAdd(&cnt[staged[e] & 63], 1);
    __syncthreads();
    if (t == 0) {
        int run = 0;
        for (int i = 0; i < 64; i++) { pos[i] = run; run += cnt[i]; }
    }
    __syncthreads();
    if (t < 64) {
        cur[t] = pos[t];
        int node = k * 64 + t;
        if (node < n) {
            offsets[node] = beg + pos[t];
            dinv[node] = 1.0f / sqrtf((float)(cnt[t] + 1));  // + self-loop
        }
    }
    __syncthreads();
    for (int e = beg + t; e < end; e += 256) {
        int pk = staged[e];
        int p = atomicAdd(&cur[pk & 63], 1);
        csr[beg + p] = (unsigned short)(pk >> 6);
    }
}

// y1[i,:] = dinv[i] * (X[i,:] @ W) stored as bf16 rows (128B = 1 line).
__global__ __launch_bounds__(256) void k_gemm_scale(const float* __restrict__ X,
                                                    const float* __restrict__ W,
                                                    const float* __restrict__ dinv,
                                                    unsigned short* __restrict__ Y, int n) {
    __shared__ float Ws[64 * 64];
    __shared__ float xs[16][64];
    int t = threadIdx.x, w = t >> 6, f = t & 63;
    const float4* W4 = (const float4*)W;
    float4* Ws4 = (float4*)Ws;
#pragma unroll
    for (int j = 0; j < 4; j++) Ws4[t + 256 * j] = W4[t + 256 * j];
    int r0 = blockIdx.x * 16;
#pragma unroll
    for (int i = 0; i < 4; i++) {
        int r = r0 + w * 4 + i;
        xs[w * 4 + i][f] = (r < n) ? X[(size_t)r * 64 + f] : 0.f;
    }
    __syncthreads();
    float acc[4] = {0.f, 0.f, 0.f, 0.f};
#pragma unroll 8
    for (int k = 0; k < 64; k++) {
        float wv = Ws[k * 64 + f];
#pragma unroll
        for (int i = 0; i < 4; i++) acc[i] += xs[w * 4 + i][k] * wv;
    }
#pragma unroll
    for (int i = 0; i < 4; i++) {
        int r = r0 + w * 4 + i;
        if (r < n) Y[(size_t)r * 64 + f] = f2bf(dinv[r] * acc[i]);
    }
}

// Layer-1 aggregate + fused GEMM2. Gather identical to R12: one wave per
// node (beg/end wave-uniform), lane=(q,c), ushort4 slot loads, unroll-4,
// shfl_xor(16,32) reduce, fp32 h. Epilogue: q==0 lanes park h row in LDS,
// one __syncthreads, lane l computes y2[node][l] = dinv*(h @ W2[:,l]) with
// the W2 column held in VGPRs (wcol, coalesced global loads issued before
// the gather; L1-resident after first block per CU). LDS per wave in the
// epilogue: 1 b128 write + 16 broadcast b128 reads (was 64 b32 + 16 b128).
__global__ __launch_bounds__(256) void k_agg_fuse(const unsigned short* __restrict__ Y,
                                                  const float* __restrict__ dinv,
                                                  const float* __restrict__ bias,
                                                  const int* __restrict__ offsets,
                                                  const unsigned short* __restrict__ csr,
                                                  const float* __restrict__ W2,
                                                  unsigned short* __restrict__ Yout, int n) {
    __shared__ float hs[4][64];     // 1 KB
    const ushort4* Y4 = (const ushort4*)Y;
    int t = threadIdx.x, w = t >> 6, l = t & 63;
    int q = l >> 4, c = l & 15;
    // W2 column l -> VGPRs. Lanes read consecutive addresses per m (coalesced
    // 256B); hidden under the gather's latency chain.
    float wcol[64];
#pragma unroll
    for (int m = 0; m < 64; m++) wcol[m] = W2[m * 64 + l];
    int node = blockIdx.x * 4 + w;
    bool valid = node < n;
    float4 hval = make_float4(0.f, 0.f, 0.f, 0.f);
    float dv = 0.f;
    if (valid) {
        float4 acc = make_float4(0.f, 0.f, 0.f, 0.f);
        if (q == 0) {  // self-loop term
            ushort4 u = Y4[(size_t)node * 16 + c];
            acc = make_float4(bf2f(u.x), bf2f(u.y), bf2f(u.z), bf2f(u.w));
        }
        int beg = offsets[node], end = offsets[node + 1];
        for (int j = beg + q; j < end; j += 16) {
#pragma unroll
            for (int u = 0; u < 4; u++) {
                int jj = j + 4 * u;
                if (jj < end) {
                    int s = csr[jj];                     // uniform within slot
                    ushort4 v = Y4[(size_t)s * 16 + c];  // 16 lanes x 8B = row
                    acc.x += bf2f(v.x); acc.y += bf2f(v.y);
                    acc.z += bf2f(v.z); acc.w += bf2f(v.w);
                }
            }
        }
#pragma unroll
        for (int m = 16; m <= 32; m <<= 1) {
            acc.x += __shfl_xor(acc.x, m);
            acc.y += __shfl_xor(acc.y, m);
            acc.z += __shfl_xor(acc.z, m);
            acc.w += __shfl_xor(acc.w, m);
        }
        dv = dinv[node];
        float4 b4 = ((const float4*)bias)[c];
        hval.x = fmaxf(dv * acc.x + b4.x, 0.f);
        hval.y = fmaxf(dv * acc.y + b4.y, 0.f);
        hval.z = fmaxf(dv * acc.z + b4.z, 0.f);
        hval.w = fmaxf(dv * acc.w + b4.w, 0.f);
    }
    if (q == 0) ((float4*)hs[w])[c] = hval;  // zeros if invalid
    __syncthreads();
    if (valid) {
        float acc2 = 0.f;
#pragma unroll
        for (int m = 0; m < 16; m++) {
            float4 h4 = ((const float4*)hs[w])[m];   // wave-broadcast
            acc2 += h4.x * wcol[4 * m + 0] + h4.y * wcol[4 * m + 1]
                  + h4.z * wcol[4 * m + 2] + h4.w * wcol[4 * m + 3];
        }
        Yout[(size_t)node * 64 + l] = f2bf(dv * acc2);
    }
}

// Layer-2 aggregate + mean folded into 8-way-split global gpart atomics
// (pattern validated in R13; removes pbuf + k_mean_final dispatch).
__global__ __launch_bounds__(256) void k_agg_pool(const unsigned short* __restrict__ Y,
                                                  const float* __restrict__ dinv,
                                                  const float* __restrict__ bias,
                                                  const int* __restrict__ offsets,
                                                  const unsigned short* __restrict__ csr,
                                                  float* __restrict__ gpart, int n) {
    __shared__ float4 sm4[4][16];
    const ushort4* Y4 = (const ushort4*)Y;
    int t = threadIdx.x, w = t >> 6, l = t & 63;
    int q = l >> 4, c = l & 15;
    int node = blockIdx.x * 4 + w;
    bool valid = node < n;
    float4 hval = make_float4(0.f, 0.f, 0.f, 0.f);
    if (valid) {
        float4 acc = make_float4(0.f, 0.f, 0.f, 0.f);
        if (q == 0) {
            ushort4 u = Y4[(size_t)node * 16 + c];
            acc = make_float4(bf2f(u.x), bf2f(u.y), bf2f(u.z), bf2f(u.w));
        }
        int beg = offsets[node], end = offsets[node + 1];
        for (int j = beg + q; j < end; j += 16) {
#pragma unroll
            for (int u = 0; u < 4; u++) {
                int jj = j + 4 * u;
                if (jj < end) {
                    int s = csr[jj];
                    ushort4 v = Y4[(size_t)s * 16 + c];
                    acc.x += bf2f(v.x); acc.y += bf2f(v.y);
                    acc.z += bf2f(v.z); acc.w += bf2f(v.w);
                }
            }
        }
#pragma unroll
        for (int m = 16; m <= 32; m <<= 1) {
            acc.x += __shfl_xor(acc.x, m);
            acc.y += __shfl_xor(acc.y, m);
            acc.z += __shfl_xor(acc.z, m);
            acc.w += __shfl_xor(acc.w, m);
        }
        float dv = dinv[node];
        float4 b4 = ((const float4*)bias)[c];
        hval.x = fmaxf(dv * acc.x + b4.x, 0.f);
        hval.y = fmaxf(dv * acc.y + b4.y, 0.f);
        hval.z = fmaxf(dv * acc.z + b4.z, 0.f);
        hval.w = fmaxf(dv * acc.w + b4.w, 0.f);
    }
    if (q == 0) sm4[w][c] = valid ? hval : make_float4(0.f, 0.f, 0.f, 0.f);
    __syncthreads();
    if (t < 16) {
        float4 a = sm4[0][t], b = sm4[1][t], d = sm4[2][t], e = sm4[3][t];
        float4 s;
        s.x = (a.x + b.x) + (d.x + e.x);
        s.y = (a.y + b.y) + (d.y + e.y);
        s.z = (a.z + b.z) + (d.z + e.z);
        s.w = (a.w + b.w) + (d.w + e.w);
        float* gp = gpart + ((blockIdx.x & 7) << 6) + 4 * t;
        atomicAdd(gp + 0, s.x);
        atomicAdd(gp + 1, s.y);
        atomicAdd(gp + 2, s.z);
        atomicAdd(gp + 3, s.w);
    }
}

__global__ void k_readout(const float* __restrict__ gpart, const float* __restrict__ Wr,
                          const float* __restrict__ br, float* __restrict__ out,
                          float invn) {
    __shared__ float gl[64];
    int t = threadIdx.x;
    if (t < 64) {
        float s = 0.f;
#pragma unroll
        for (int j = 0; j < 8; j++) s += gpart[j * 64 + t];
        gl[t] = s * invn;
    }
    __syncthreads();
    float acc = br[t];
#pragma unroll
    for (int k = 0; k < 64; k++) acc += gl[k] * Wr[k * 128 + t];
    out[t] = acc;
}

extern "C" void kernel_launch(void* const* d_in, const int* in_sizes, int n_in,
                              void* d_out, int out_size, void* d_ws, size_t ws_size,
                              hipStream_t stream) {
    const float* x  = (const float*)d_in[0];
    const int*   ei = (const int*)d_in[1];   // int32 on device (JAX x64 off)
    const float* W1 = (const float*)d_in[2];
    const float* b1 = (const float*)d_in[3];
    const float* W2 = (const float*)d_in[4];
    const float* b2 = (const float*)d_in[5];
    const float* Wr = (const float*)d_in[6];
    const float* br = (const float*)d_in[7];
    float* out = (float*)d_out;

    int n = in_sizes[0] / 64;   // 50000
    int E = in_sizes[1] / 2;    // 800000
    const int* src = ei;
    const int* dst = ei + E;

    int NB  = (n + 63) / 64;       // 782 buckets of 64 nodes
    int nch = (E + CH - 1) / CH;   // 196 chunks

    // workspace layout (~19 MB)
    char* p = (char*)d_ws;
    unsigned short* y1 = (unsigned short*)p; p += (size_t)n * 64 * sizeof(unsigned short);
    unsigned short* y2 = (unsigned short*)p; p += (size_t)n * 64 * sizeof(unsigned short);
    float* dinv = (float*)p;   p += (size_t)n * sizeof(float);
    float* gpart = (float*)p;  p += 512 * sizeof(float);
    int* staged = (int*)p;     p += (size_t)E * sizeof(int);
    int* offsets = (int*)p;    p += (size_t)(n + 1) * sizeof(int);
    int* histmat = (int*)p;    p += (size_t)nch * NB * sizeof(int);
    int* bstart = (int*)p;     p += (size_t)(NB + 1) * sizeof(int);
    unsigned short* csr = (unsigned short*)p; p += (size_t)E * sizeof(unsigned short);

    k_bucket_hist<<<nch, 256, 0, stream>>>(dst, histmat, E, NB);
    k_scan<<<1, 1024, 0, stream>>>(histmat, bstart, offsets, gpart, NB, nch, E, n);
    k_bucket_scatter<<<nch, 256, 0, stream>>>(src, dst, histmat, bstart, staged, E, NB);
    k_local_sort<<<NB, 256, 0, stream>>>(staged, bstart, csr, offsets, dinv, n);

    int gb = (n + 3) / 4;  // 12500 aggregate blocks (one wave per node)
    k_gemm_scale<<<(n + 15) / 16, 256, 0, stream>>>(x, W1, dinv, y1, n);
    k_agg_fuse<<<gb, 256, 0, stream>>>(y1, dinv, b1, offsets, csr, W2, y2, n);
    k_agg_pool<<<gb, 256, 0, stream>>>(y2, dinv, b2, offsets, csr, gpart, n);

    k_readout<<<1, 128, 0, stream>>>(gpart, Wr, br, out, 1.0f / (float)n);
}